// Round 12
// baseline (746.552 us; speedup 1.0000x reference)
//
#include <hip/hip_runtime.h>
#include <hip/hip_bf16.h>
#include <math.h>

// ---------------- problem constants ----------------
constexpr int B_    = 64;
constexpr int C_    = 192;
constexpr int N_    = 576;    // nodes per image (24x24)
constexpr int BN_   = B_ * N_;      // 36864
constexpr int K_    = 5;
constexpr int E_    = BN_ * K_;     // 184320

__device__ __forceinline__ float gelu_exact(float x) {
    return 0.5f * x * (1.0f + erff(x * 0.70710678118654752440f));
}

__device__ __forceinline__ float bf2f(unsigned short v) {
    return __uint_as_float(((unsigned)v) << 16);
}
__device__ __forceinline__ unsigned short f2bf(float x) {
    __hip_bfloat16 h = __float2bfloat16(x);
    return *(unsigned short*)&h;
}

// ---------------- fused weight prep: 6 kernels -> 1 launch ----------------
__global__ __launch_bounds__(256) void prep_all_k(
    const float* __restrict__ stem_w, const float* __restrict__ gnn_w1,
    const float* __restrict__ gnn_w2, const float* __restrict__ ffn_w1,
    const float* __restrict__ ffn_w2, const float* __restrict__ att_w1,
    float* __restrict__ wt, unsigned short* __restrict__ wg1T,
    unsigned short* __restrict__ wg2T, unsigned short* __restrict__ wf1T,
    unsigned short* __restrict__ wf2T, unsigned short* __restrict__ waHi,
    unsigned short* __restrict__ waLo)
{
    int gid = blockIdx.x * 256 + threadIdx.x;        // < 589824
    if (gid < 147456) {                              // transpose_w
        int k = gid / 192, oc = gid % 192;
        wt[gid] = stem_w[oc * 768 + k];
    } else if (gid < 184320) {                       // wg1
        int g = gid - 147456;
        int n = g / 192, k = g % 192;
        wg1T[g] = f2bf(gnn_w1[(size_t)k * 192 + n]);
    } else if (gid < 221184) {                       // wg2
        int g = gid - 184320;
        int n = g / 192, k = g % 192;
        wg2T[g] = f2bf(gnn_w2[(size_t)k * 192 + n]);
    } else if (gid < 368640) {                       // wf1 (K=192,N=768)
        int g = gid - 221184;
        int n = g / 192, k = g % 192;
        wf1T[g] = f2bf(ffn_w1[(size_t)k * 768 + n]);
    } else if (gid < 516096) {                       // wf2 (K=768,N=192)
        int g = gid - 368640;
        int n = g / 768, k = g % 768;
        wf2T[g] = f2bf(ffn_w2[(size_t)k * 192 + n]);
    } else {                                         // wsplit att
        int g = gid - 516096;                        // < 73728
        int half = g / 36864, r = g % 36864;
        int n = r / 192, k = r % 192;
        float v = att_w1[(size_t)(half * 192 + k) * 192 + n];
        unsigned short h = f2bf(v);
        waHi[g] = h;
        waLo[g] = f2bf(v - bf2f(h));
    }
}

// ---------------- stem: 96-row tile GEMM + asplit-only fusion (proven R10) ----------------
__global__ __launch_bounds__(256) void stem_gemm96a_k(
    const float* __restrict__ x, const float* __restrict__ Wt,
    const float* __restrict__ sb, const float* __restrict__ pos,
    float* __restrict__ nf,
    unsigned short* __restrict__ ahi, unsigned short* __restrict__ alo)
{
    __shared__ float As[96][68];
    __shared__ float Ws[64][68];
    const int tid = threadIdx.x;
    const int tr = tid >> 4, tc = tid & 15;
    const int mb = blockIdx.x;          // 0..383 (64 images x 6 tiles of 96)
    const int nb = blockIdx.y;          // 0..2 oc blocks
    const int b  = mb / 6;
    const int n0 = (mb % 6) * 96;       // node offset within image

    float4 acc[6];
    #pragma unroll
    for (int i = 0; i < 6; ++i) acc[i] = float4{0.f, 0.f, 0.f, 0.f};

    for (int kc = 0; kc < 768; kc += 64) {
        #pragma unroll
        for (int i = 0; i < 6; ++i) {
            int q = i * 256 + tid;
            int m = q >> 4, kq = q & 15;       // m < 96
            int k = kc + kq * 4;
            int ci = k >> 8, rem = k & 255, dy = rem >> 4, dx = rem & 15;
            int n = n0 + m, py = n / 24, px = n % 24;
            const float* src = &x[(((size_t)(b * 3 + ci) * 384) + py * 16 + dy) * 384
                                  + px * 16 + dx];
            *(float4*)&As[m][kq * 4] = *(const float4*)src;
        }
        #pragma unroll
        for (int i = 0; i < 4; ++i) {
            int q = i * 256 + tid;
            int m = q >> 4, kq = q & 15;       // m < 64
            *(float4*)&Ws[m][kq * 4] =
                *(const float4*)&Wt[(size_t)(kc + m) * 192 + nb * 64 + kq * 4];
        }
        __syncthreads();
        #pragma unroll
        for (int k4 = 0; k4 < 64; k4 += 4) {
            float4 a4[6], b4[4];
            #pragma unroll
            for (int i = 0; i < 6; ++i) a4[i] = *(const float4*)&As[tr * 6 + i][k4];
            #pragma unroll
            for (int kk = 0; kk < 4; ++kk) b4[kk] = *(const float4*)&Ws[k4 + kk][tc * 4];
            #pragma unroll
            for (int i = 0; i < 6; ++i) {
                const float av[4] = {a4[i].x, a4[i].y, a4[i].z, a4[i].w};
                #pragma unroll
                for (int kk = 0; kk < 4; ++kk) {
                    acc[i].x += av[kk] * b4[kk].x;
                    acc[i].y += av[kk] * b4[kk].y;
                    acc[i].z += av[kk] * b4[kk].z;
                    acc[i].w += av[kk] * b4[kk].w;
                }
            }
        }
        __syncthreads();
    }

    #pragma unroll
    for (int i = 0; i < 6; ++i) {
        int n = n0 + tr * 6 + i;
        int row = b * 576 + n;
        int oc0 = nb * 64 + tc * 4;
        float v[4] = {acc[i].x, acc[i].y, acc[i].z, acc[i].w};
        unsigned short hv[4], lv[4];
        #pragma unroll
        for (int j = 0; j < 4; ++j) {
            int oc = oc0 + j;
            v[j] = v[j] + sb[oc] + pos[oc * 576 + n];
            hv[j] = f2bf(v[j]);
            lv[j] = f2bf(v[j] - bf2f(hv[j]));
        }
        *(float4*)&nf[(size_t)row * 192 + oc0] = float4{v[0], v[1], v[2], v[3]};
        *(ushort4*)&ahi[(size_t)row * 192 + oc0] = ushort4{hv[0], hv[1], hv[2], hv[3]};
        *(ushort4*)&alo[(size_t)row * 192 + oc0] = ushort4{lv[0], lv[1], lv[2], lv[3]};
    }
}

// ---------------- transpose nf per image (proven) ----------------
__global__ void transpose_nf_k(const float* __restrict__ nf, float* __restrict__ nfT) {
    __shared__ float tile[32][33];
    int b = blockIdx.z;
    int n0 = blockIdx.x * 32, c0 = blockIdx.y * 32;
    int tx = threadIdx.x, ty = threadIdx.y;   // 32 x 8
    #pragma unroll
    for (int r = 0; r < 4; ++r) {
        int i = ty * 4 + r;
        tile[i][tx] = nf[((size_t)b * 576 + n0 + i) * 192 + c0 + tx];
    }
    __syncthreads();
    #pragma unroll
    for (int r = 0; r < 4; ++r) {
        int i = ty * 4 + r;
        nfT[((size_t)b * 192 + c0 + i) * 576 + n0 + tx] = tile[tx][i];
    }
}

// ---------------- sq norms per node (UNCHANGED) ----------------
__global__ __launch_bounds__(256) void sq_k(const float* __restrict__ nf,
                                            float* __restrict__ sq) {
    int wid = threadIdx.x >> 6, lane = threadIdx.x & 63;
    int n = blockIdx.x * 4 + wid;
    const float* row = nf + (size_t)n * 192;
    float s = 0.f;
    #pragma unroll
    for (int c = 0; c < 3; ++c) { float v = row[lane + c * 64]; s += v * v; }
    #pragma unroll
    for (int off = 32; off; off >>= 1) s += __shfl_down(s, off);
    if (lane == 0) sq[n] = s;
}

// ---------------- kNN symmetric-triangle, 128-thread / 2-wave blocks ----------------
// Same 64x64 tile, same per-output k-ascending FMA chain, same staged
// values, same d2 epilogue expression, same ascending strict-< selection
// -> bit-identical to the R1 64-thread version.  Structural changes only:
//  - 2 waves/block: wave w owns 32 rows, 4x8 outputs/thread (acc 64->32
//    VGPRs); LDS unchanged 17.7KB -> 9 blocks/CU = 4.5 waves/SIMD (was
//    2.25 — the kernel was occupancy/latency-bound at 17% issue eff.)
//  - pass A (threads 0-63) and pass B (threads 64-127) selection scans
//    run CONCURRENTLY (disjoint candV/candI regions)
__global__ __launch_bounds__(128) void knn_sym_k(
    const float* __restrict__ nfT, const float* __restrict__ sqn,
    float* __restrict__ candV, int* __restrict__ candI)
{
    __shared__ float smem[64 * 69];          // 17664 B
    float* As  = smem;                       // [32][64] k-major (GEMM phase)
    float* Bs  = smem + 2048;                // [32][64]
    float* d2s = smem;                       // [64][69] (selection phase)

    const int tid = threadIdx.x;             // 0..127
    const int w = tid >> 6;                  // wave: row half
    const int lane = tid & 63;
    const int tr4 = lane >> 3, tc = lane & 7;
    const int b = blockIdx.y;
    int t = blockIdx.x;                      // 0..44 upper-triangle tile id
    int bi = 0;
    while (t >= 9 - bi) { t -= 9 - bi; ++bi; }
    const int bj = bi + t;
    const int r0 = bi * 64, c0 = bj * 64;

    float acc[4][8];                         // rows w*32+tr4*4+i, cols tc*8+j
    #pragma unroll
    for (int i = 0; i < 4; ++i)
        #pragma unroll
        for (int j = 0; j < 8; ++j) acc[i][j] = 0.f;

    for (int kc = 0; kc < 192; kc += 32) {
        // stage 32 k-rows x 64 nodes for each operand (coalesced; values
        // and destinations identical to the 64-thread version)
        #pragma unroll
        for (int i = 0; i < 4; ++i) {
            int q = i * 128 + tid;           // 0..511
            int k = q >> 4, c4 = (q & 15) * 4;
            const float* srow = &nfT[((size_t)(b * 192 + kc + k)) * 576];
            *(float4*)&As[k * 64 + c4] = *(const float4*)&srow[r0 + c4];
            *(float4*)&Bs[k * 64 + c4] = *(const float4*)&srow[c0 + c4];
        }
        __syncthreads();
        #pragma unroll 8
        for (int kk = 0; kk < 32; ++kk) {
            float4 a  = *(const float4*)&As[kk * 64 + w * 32 + tr4 * 4];
            float4 b0 = *(const float4*)&Bs[kk * 64 + tc * 8];
            float4 b1 = *(const float4*)&Bs[kk * 64 + tc * 8 + 4];
            const float av[4] = {a.x, a.y, a.z, a.w};
            const float bv[8] = {b0.x, b0.y, b0.z, b0.w, b1.x, b1.y, b1.z, b1.w};
            #pragma unroll
            for (int i = 0; i < 4; ++i)
                #pragma unroll
                for (int j = 0; j < 8; ++j)
                    acc[i][j] += av[i] * bv[j];
        }
        __syncthreads();
    }

    // epilogue into LDS (overlays As/Bs — synced above)
    #pragma unroll
    for (int i = 0; i < 4; ++i) {
        int rl = w * 32 + tr4 * 4 + i, rg = r0 + rl;
        float sr = sqn[b * 576 + rg];
        #pragma unroll
        for (int j = 0; j < 8; ++j) {
            int cl = tc * 8 + j, cg = c0 + cl;
            float d = sr + sqn[b * 576 + cg] - 2.f * acc[i][j];
            if (cg == rg) d += 1e9f;
            d2s[rl * 69 + cl] = d;
        }
    }
    __syncthreads();

    // pass A (threads 0-63): row r=tid, ascending col scan — identical math
    if (tid < 64) {
        const int r = tid;
        float tv[5]; int ti[5];
        #pragma unroll
        for (int p = 0; p < 5; ++p) { tv[p] = 3.4e38f; ti[p] = 0; }
        for (int c = 0; c < 64; ++c) {
            float cv = d2s[r * 69 + c];
            if (cv < tv[4]) {
                int ci = c0 + c;
                #pragma unroll
                for (int q = 0; q < 5; ++q) {       // stable sorted insert (strict <)
                    bool less = cv < tv[q];
                    float nv = less ? tv[q] : cv;
                    int ni   = less ? ti[q] : ci;
                    tv[q] = less ? cv : tv[q];
                    ti[q] = less ? ci : ti[q];
                    cv = nv; ci = ni;
                }
            }
        }
        int gr = b * 576 + r0 + r;
        #pragma unroll
        for (int p = 0; p < 5; ++p) {
            candV[(size_t)gr * 45 + bj * 5 + p] = tv[p];
            candI[(size_t)gr * 45 + bj * 5 + p] = ti[p];
        }
    } else if (bi != bj) {
        // pass B (threads 64-127): col c, ascending row scan — identical math
        const int c = tid - 64;
        float tv[5]; int ti[5];
        #pragma unroll
        for (int p = 0; p < 5; ++p) { tv[p] = 3.4e38f; ti[p] = 0; }
        for (int r = 0; r < 64; ++r) {
            float cv = d2s[r * 69 + c];          // transposed read, conflict-free
            if (cv < tv[4]) {
                int ci = r0 + r;
                #pragma unroll
                for (int q = 0; q < 5; ++q) {
                    bool less = cv < tv[q];
                    float nv = less ? tv[q] : cv;
                    int ni   = less ? ti[q] : ci;
                    tv[q] = less ? cv : tv[q];
                    ti[q] = less ? ci : ti[q];
                    cv = nv; ci = ni;
                }
            }
        }
        int gr = b * 576 + c0 + c;
        #pragma unroll
        for (int p = 0; p < 5; ++p) {
            candV[(size_t)gr * 45 + bi * 5 + p] = tv[p];
            candI[(size_t)gr * 45 + bi * 5 + p] = ti[p];
        }
    }
}

// ---------------- kNN merge: 9 groups x 5 sorted candidates -> final top-5 ----------------
__global__ __launch_bounds__(256) void knn_merge_k(
    const float* __restrict__ candV, const int* __restrict__ candI,
    int* __restrict__ idxOut)
{
    int r = blockIdx.x * 256 + threadIdx.x;    // < BN_
    float tv[5]; int ti[5];
    #pragma unroll
    for (int p = 0; p < 5; ++p) { tv[p] = 3.4e38f; ti[p] = 0; }
    #pragma unroll 5
    for (int s = 0; s < 45; ++s) {
        float cv = candV[(size_t)r * 45 + s];
        if (cv < tv[4]) {
            int cidx = candI[(size_t)r * 45 + s];
            #pragma unroll
            for (int q = 0; q < 5; ++q) {
                bool less = cv < tv[q];
                float nv = less ? tv[q] : cv;
                int ni   = less ? ti[q] : cidx;
                tv[q] = less ? cv : tv[q];
                ti[q] = less ? cidx : ti[q];
                cv = nv; cidx = ni;
            }
        }
    }
    int base = (r / 576) * 576;
    #pragma unroll
    for (int p = 0; p < 5; ++p) idxOut[r * 5 + p] = base + ti[p];
}

// ---------------- generic 64x64-tile f32 GEMM (head) ----------------
template <int EPI>
__global__ __launch_bounds__(256) void gemm_rm_k(
    const float* __restrict__ A, const float* __restrict__ W, float* __restrict__ out,
    int M, int N, int K,
    const float* __restrict__ bias, const float* __restrict__ gsc,
    const float* __restrict__ gsh, const float* __restrict__ res)
{
    __shared__ float As[64][68];
    __shared__ float Ws[64][68];
    const int tid = threadIdx.x;
    const int tr = tid >> 4, tc = tid & 15;
    const int mBase = blockIdx.x * 64, nBase = blockIdx.y * 64;

    float4 acc[4];
    acc[0] = acc[1] = acc[2] = acc[3] = float4{0.f, 0.f, 0.f, 0.f};

    for (int kc = 0; kc < K; kc += 64) {
        #pragma unroll
        for (int i = 0; i < 4; ++i) {
            int q = i * 256 + tid;
            int m = q >> 4, kq = q & 15;
            *(float4*)&As[m][kq * 4] =
                *(const float4*)&A[(size_t)(mBase + m) * K + kc + kq * 4];
            *(float4*)&Ws[m][kq * 4] =
                *(const float4*)&W[(size_t)(kc + m) * N + nBase + kq * 4];
        }
        __syncthreads();
        #pragma unroll
        for (int k4 = 0; k4 < 64; k4 += 4) {
            float4 a4[4], b4[4];
            #pragma unroll
            for (int i = 0; i < 4; ++i) a4[i] = *(const float4*)&As[tr * 4 + i][k4];
            #pragma unroll
            for (int kk = 0; kk < 4; ++kk) b4[kk] = *(const float4*)&Ws[k4 + kk][tc * 4];
            #pragma unroll
            for (int i = 0; i < 4; ++i) {
                const float av[4] = {a4[i].x, a4[i].y, a4[i].z, a4[i].w};
                #pragma unroll
                for (int kk = 0; kk < 4; ++kk) {
                    acc[i].x += av[kk] * b4[kk].x;
                    acc[i].y += av[kk] * b4[kk].y;
                    acc[i].z += av[kk] * b4[kk].z;
                    acc[i].w += av[kk] * b4[kk].w;
                }
            }
        }
        __syncthreads();
    }

    #pragma unroll
    for (int i = 0; i < 4; ++i) {
        int row = mBase + tr * 4 + i;
        int n0 = nBase + tc * 4;
        float v[4] = {acc[i].x, acc[i].y, acc[i].z, acc[i].w};
        #pragma unroll
        for (int j = 0; j < 4; ++j) {
            int n = n0 + j;
            float xv = v[j];
            if (EPI == 1) xv += bias[n];
            if (EPI == 2) { xv += bias[n]; xv = fmaxf(xv, 0.f); }
            if (EPI == 3) { xv = (xv + bias[n]) * gsc[n] + gsh[n]; xv = gelu_exact(xv); }
            if (EPI == 4) {
                xv = res[(size_t)row * N + n] + (xv + bias[n]) * gsc[n] + gsh[n];
            }
            v[j] = xv;
        }
        *(float4*)&out[(size_t)row * N + n0] = float4{v[0], v[1], v[2], v[3]};
    }
}

// ---------------- bf16 MFMA GEMM, 256x64 tile (proven R4) ----------------
template <int EPI>
__global__ __launch_bounds__(256) void gemm_mfma_k(
    const unsigned short* __restrict__ A, const unsigned short* __restrict__ Bt,
    unsigned short* __restrict__ out, int M, int N, int K,
    const float* __restrict__ bias, const float* __restrict__ gsc,
    const float* __restrict__ gsh, const unsigned short* __restrict__ res)
{
    using frag = __attribute__((ext_vector_type(8))) short;
    using facc = __attribute__((ext_vector_type(4))) float;
    __shared__ unsigned short As[256][72];  // [m][k]  36.9KB
    __shared__ unsigned short Bs[64][72];   // [n][k]   9.2KB
    const int tid = threadIdx.x;
    const int wave = tid >> 6, lane = tid & 63;
    const int m16 = lane & 15, quad = lane >> 4;
    const int mBase = blockIdx.x * 256, nBase = blockIdx.y * 64;

    facc zero = {0.f, 0.f, 0.f, 0.f};
    facc acc[4][4];                         // [m-slice][n-tile]
    #pragma unroll
    for (int ms = 0; ms < 4; ++ms)
        #pragma unroll
        for (int t = 0; t < 4; ++t) acc[ms][t] = zero;

    for (int kc = 0; kc < K; kc += 64) {
        #pragma unroll
        for (int r = 0; r < 8; ++r) {       // A: 256 rows x 64 k
            int q = r * 256 + tid;          // 0..2047
            int row = q >> 3, c8 = (q & 7) * 8;
            *(int4*)&As[row][c8] =
                *(const int4*)&A[(size_t)(mBase + row) * K + kc + c8];
        }
        #pragma unroll
        for (int r = 0; r < 2; ++r) {       // B: 64 rows x 64 k
            int q = r * 256 + tid;          // 0..511
            int row = q >> 3, c8 = (q & 7) * 8;
            *(int4*)&Bs[row][c8] =
                *(const int4*)&Bt[(size_t)(nBase + row) * K + kc + c8];
        }
        __syncthreads();
        #pragma unroll
        for (int kk = 0; kk < 64; kk += 32) {
            frag bfr[4];
            #pragma unroll
            for (int t = 0; t < 4; ++t)
                bfr[t] = *(const frag*)&Bs[t * 16 + m16][kk + quad * 8];
            #pragma unroll
            for (int ms = 0; ms < 4; ++ms) {
                frag a = *(const frag*)&As[64 * wave + ms * 16 + m16][kk + quad * 8];
                #pragma unroll
                for (int t = 0; t < 4; ++t)
                    acc[ms][t] = __builtin_amdgcn_mfma_f32_16x16x32_bf16(a, bfr[t], acc[ms][t], 0, 0, 0);
            }
        }
        __syncthreads();
    }

    #pragma unroll
    for (int ms = 0; ms < 4; ++ms) {
        #pragma unroll
        for (int t = 0; t < 4; ++t) {
            #pragma unroll
            for (int r = 0; r < 4; ++r) {
                int row = mBase + 64 * wave + ms * 16 + quad * 4 + r;
                int col = nBase + t * 16 + m16;
                float xv = acc[ms][t][r];
                if (EPI == 2) { xv += bias[col]; xv = fmaxf(xv, 0.f); }
                if (EPI == 3) { xv = (xv + bias[col]) * gsc[col] + gsh[col]; xv = gelu_exact(xv); }
                if (EPI == 4) {
                    xv = bf2f(res[(size_t)row * N + col]) + (xv + bias[col]) * gsc[col] + gsh[col];
                }
                out[(size_t)row * N + col] = f2bf(xv);
            }
        }
    }
}

// ---------------- merged split-bf16 MFMA GEMM: both att halves in ONE launch ----------------
__global__ __launch_bounds__(256) void gemm_mfma_split2_k(
    const unsigned short* __restrict__ Ah, const unsigned short* __restrict__ Al,
    const unsigned short* __restrict__ waHi, const unsigned short* __restrict__ waLo,
    float* __restrict__ outA, float* __restrict__ outB,
    const float* __restrict__ bias)
{
    using frag = __attribute__((ext_vector_type(8))) short;
    using facc = __attribute__((ext_vector_type(4))) float;
    __shared__ unsigned short AsH[128][72], AsL[128][72];   // 2x18.4KB
    __shared__ unsigned short BsH[64][72],  BsL[64][72];    // 2x9.2KB
    const int tid = threadIdx.x;
    const int wave = tid >> 6, lane = tid & 63;
    const int m16 = lane & 15, quad = lane >> 4;
    const int half = blockIdx.y / 3;
    const int mBase = blockIdx.x * 128, nBase = (blockIdx.y % 3) * 64;
    const unsigned short* Bh = waHi + half * 36864;
    const unsigned short* Bl = waLo + half * 36864;
    float* out = half ? outB : outA;
    constexpr int K = 192;

    facc zero = {0.f, 0.f, 0.f, 0.f};
    facc acc[2][4];                         // [m-slice][n-tile]
    #pragma unroll
    for (int ms = 0; ms < 2; ++ms)
        #pragma unroll
        for (int t = 0; t < 4; ++t) acc[ms][t] = zero;

    for (int kc = 0; kc < K; kc += 64) {
        #pragma unroll
        for (int r = 0; r < 4; ++r) {       // A: 128 rows x 64 k per buffer
            int q = r * 256 + tid;          // 0..1023
            int row = q >> 3, c8 = (q & 7) * 8;
            *(int4*)&AsH[row][c8] = *(const int4*)&Ah[(size_t)(mBase + row) * K + kc + c8];
            *(int4*)&AsL[row][c8] = *(const int4*)&Al[(size_t)(mBase + row) * K + kc + c8];
        }
        #pragma unroll
        for (int r = 0; r < 2; ++r) {       // B: 64 rows x 64 k per buffer
            int q = r * 256 + tid;          // 0..511
            int row = q >> 3, c8 = (q & 7) * 8;
            *(int4*)&BsH[row][c8] = *(const int4*)&Bh[(size_t)(nBase + row) * K + kc + c8];
            *(int4*)&BsL[row][c8] = *(const int4*)&Bl[(size_t)(nBase + row) * K + kc + c8];
        }
        __syncthreads();
        #pragma unroll
        for (int kk = 0; kk < 64; kk += 32) {
            frag bh[4], bl[4];
            #pragma unroll
            for (int t = 0; t < 4; ++t) {
                bh[t] = *(const frag*)&BsH[t * 16 + m16][kk + quad * 8];
                bl[t] = *(const frag*)&BsL[t * 16 + m16][kk + quad * 8];
            }
            #pragma unroll
            for (int ms = 0; ms < 2; ++ms) {
                frag ah = *(const frag*)&AsH[32 * wave + ms * 16 + m16][kk + quad * 8];
                frag al = *(const frag*)&AsL[32 * wave + ms * 16 + m16][kk + quad * 8];
                #pragma unroll
                for (int t = 0; t < 4; ++t) {
                    acc[ms][t] = __builtin_amdgcn_mfma_f32_16x16x32_bf16(ah, bh[t], acc[ms][t], 0, 0, 0);
                    acc[ms][t] = __builtin_amdgcn_mfma_f32_16x16x32_bf16(ah, bl[t], acc[ms][t], 0, 0, 0);
                    acc[ms][t] = __builtin_amdgcn_mfma_f32_16x16x32_bf16(al, bh[t], acc[ms][t], 0, 0, 0);
                }
            }
        }
        __syncthreads();
    }

    #pragma unroll
    for (int ms = 0; ms < 2; ++ms) {
        #pragma unroll
        for (int t = 0; t < 4; ++t) {
            #pragma unroll
            for (int r = 0; r < 4; ++r) {
                int row = mBase + 32 * wave + ms * 16 + quad * 4 + r;
                int col = nBase + t * 16 + m16;
                float xv = acc[ms][t][r];
                if (half) xv += bias[col];
                out[(size_t)row * 192 + col] = xv;
            }
        }
    }
}

// ---------------- edge attention (UNCHANGED) ----------------
__global__ __launch_bounds__(256) void edge_att_k(
    const float* __restrict__ hA, const float* __restrict__ hB,
    const int* __restrict__ idx, const float* __restrict__ w2,
    const float* __restrict__ b2, float* __restrict__ att)
{
    int wid = threadIdx.x >> 6, lane = threadIdx.x & 63;
    int e = blockIdx.x * 4 + wid;
    int dst = e / K_;
    int src = idx[e];
    float s = 0.f;
    #pragma unroll
    for (int c0 = 0; c0 < 3; ++c0) {
        int c = lane + c0 * 64;
        float v = hA[(size_t)src * 192 + c] + hB[(size_t)dst * 192 + c];
        v = fmaxf(v, 0.f);
        s += v * w2[c];
    }
    #pragma unroll
    for (int off = 32; off; off >>= 1) s += __shfl_down(s, off);
    if (lane == 0) att[e] = 1.f / (1.f + expf(-(s + b2[0])));
}

// ---------------- message passing v2: 4 channels/thread, vectorized ----------------
__device__ __forceinline__ void ldv4(const float* p, size_t i, float* o) {
    float4 v = *(const float4*)&p[i];
    o[0] = v.x; o[1] = v.y; o[2] = v.z; o[3] = v.w;
}
__device__ __forceinline__ void ldv4(const unsigned short* p, size_t i, float* o) {
    ushort4 v = *(const ushort4*)&p[i];
    o[0] = bf2f(v.x); o[1] = bf2f(v.y); o[2] = bf2f(v.z); o[3] = bf2f(v.w);
}

template <typename TI>
__global__ __launch_bounds__(256) void msg_bf4_k(
    const TI* __restrict__ h, const float* __restrict__ att,
    const int* __restrict__ idx, unsigned short* __restrict__ s)
{
    int g4 = blockIdx.x * 256 + threadIdx.x;   // < BN*48
    int n = g4 / 48, c4 = (g4 % 48) * 4;
    int sp[K_]; float aw[K_];
    #pragma unroll
    for (int p = 0; p < K_; ++p) {
        sp[p] = idx[n * K_ + p];
        aw[p] = att[n * K_ + p];
    }
    float acc[4];
    ldv4(h, (size_t)n * 192 + c4, acc);
    #pragma unroll
    for (int p = 0; p < K_; ++p) {
        float v[4];
        ldv4(h, (size_t)sp[p] * 192 + c4, v);
        #pragma unroll
        for (int j = 0; j < 4; ++j) acc[j] += aw[p] * v[j];
    }
    ushort4 o;
    o.x = f2bf(acc[0]); o.y = f2bf(acc[1]); o.z = f2bf(acc[2]); o.w = f2bf(acc[3]);
    *(ushort4*)&s[(size_t)n * 192 + c4] = o;
}

// ---------------- global average pool over nodes (bf16 in) ----------------
__global__ void pool_bf16_k(const unsigned short* __restrict__ t, float* __restrict__ g) {
    int b = blockIdx.x, c = threadIdx.x;   // 192 threads
    float s = 0.f;
    for (int n = 0; n < 576; ++n) s += bf2f(t[((size_t)b * 576 + n) * 192 + c]);
    g[b * 192 + c] = s * (1.f / 576.f);
}

// ---------------- head reduce (UNCHANGED) ----------------
__global__ __launch_bounds__(256) void head2_k(
    const float* __restrict__ p, const float* __restrict__ w2,
    const float* __restrict__ b2, float* __restrict__ out)
{
    int b = blockIdx.x;
    float s = 0.f;
    for (int j = threadIdx.x; j < 1024; j += 256) s += p[(size_t)b * 1024 + j] * w2[j];
    #pragma unroll
    for (int off = 32; off; off >>= 1) s += __shfl_down(s, off);
    __shared__ float ls[4];
    int wid = threadIdx.x >> 6, lane = threadIdx.x & 63;
    if (lane == 0) ls[wid] = s;
    __syncthreads();
    if (threadIdx.x == 0) out[b] = ls[0] + ls[1] + ls[2] + ls[3] + b2[0];
}

// ---------------- launch ----------------
extern "C" void kernel_launch(void* const* d_in, const int* in_sizes, int n_in,
                              void* d_out, int out_size, void* d_ws, size_t ws_size,
                              hipStream_t stream) {
    const float* x        = (const float*)d_in[0];
    const float* stem_w   = (const float*)d_in[1];
    const float* stem_b   = (const float*)d_in[2];
    const float* pos      = (const float*)d_in[3];
    const float* att_w1   = (const float*)d_in[4];
    const float* att_b1   = (const float*)d_in[5];
    const float* att_w2   = (const float*)d_in[6];
    const float* att_b2   = (const float*)d_in[7];
    const float* gnn_w1   = (const float*)d_in[8];
    const float* gnn_b1   = (const float*)d_in[9];
    const float* gnn_w2   = (const float*)d_in[10];
    const float* gnn_b2   = (const float*)d_in[11];
    const float* ffn_w1   = (const float*)d_in[12];
    const float* ffn_b1   = (const float*)d_in[13];
    const float* ffn_g1   = (const float*)d_in[14];
    const float* ffn_be1  = (const float*)d_in[15];
    const float* ffn_w2   = (const float*)d_in[16];
    const float* ffn_b2   = (const float*)d_in[17];
    const float* ffn_g2   = (const float*)d_in[18];
    const float* ffn_be2  = (const float*)d_in[19];
    const float* pred_w1  = (const float*)d_in[20];
    const float* pred_b1  = (const float*)d_in[21];
    const float* pred_g   = (const float*)d_in[22];
    const float* pred_be  = (const float*)d_in[23];
    const float* pred_w2  = (const float*)d_in[24];
    const float* pred_b2  = (const float*)d_in[25];

    float* ws = (float*)d_ws;
    const size_t RSZ = (size_t)BN_ * C_;          // 7,077,888 floats
    float* R0 = ws;               // nf (f32) — dead after msg layer 1 -> U (FFN)
    float* R1 = R0 + RSZ;         // cand -> hA -> [Sb | Hb] -> U (FFN, with R0)
    float* R2 = R1 + RSZ;         // hB (f32) -> [Tb | ToutB] bf16
    float* R3 = R2 + RSZ;         // nfT
    float* sqb = R3 + RSZ;        // BN
    int*   idxb = (int*)(sqb + BN_);              // E ints
    float* gb = (float*)(idxb + E_);              // 64*192
    float* pb = gb + 64 * C_;                     // 64*1024
    unsigned short* wg1T = (unsigned short*)(pb + 64 * 1024);  // [192][192]
    unsigned short* wg2T = wg1T + 192 * 192;
    unsigned short* wf1T = wg2T + 192 * 192;      // [768][192]
    unsigned short* wf2T = wf1T + 768 * 192;      // [192][768]
    unsigned short* waHi = wf2T + 192 * 768;      // [2][192][192]
    unsigned short* waLo = waHi + 2 * 192 * 192;
    float* Wt = (float*)(waLo + 2 * 192 * 192);   // stem Wt [768][192] (dedicated)
    unsigned short* Ahi = (unsigned short*)(Wt + 768 * 192);   // BN x 192 bf16 hi
    unsigned short* Alo = Ahi + RSZ;                            // BN x 192 bf16 lo

    // kNN candidate buffers live in R1 (dead before R1's next use in step 3)
    float* candV = R1;                                   // BN x 45
    int*   candI = (int*)(R1 + (size_t)BN_ * 45);        // BN x 45

    unsigned short* Sb    = (unsigned short*)R1;             // BN x 192 bf16
    unsigned short* Hb    = (unsigned short*)(R1 + RSZ / 2);
    unsigned short* Tb    = (unsigned short*)R2;
    unsigned short* ToutB = (unsigned short*)(R2 + RSZ / 2);
    // full-size FFN intermediate: BN x 768 bf16 = 56.6MB = R0+R1 exactly
    unsigned short* U     = (unsigned short*)R0;

    float* att  = (float*)d_out;                  // E
    float* pred = att + E_;                       // 64

    // 0. all weight prep in ONE launch
    prep_all_k<<<2304, 256, 0, stream>>>(stem_w, gnn_w1, gnn_w2, ffn_w1,
        ffn_w2, att_w1, Wt, wg1T, wg2T, wf1T, wf2T, waHi, waLo);

    // 1. stem (proven 96-row tile, bit-frozen FMA chain) + asplit-only fusion
    stem_gemm96a_k<<<dim3(384, 3), 256, 0, stream>>>(x, Wt, stem_b, pos,
        R0, Ahi, Alo);

    // 2. kNN graph (d2 math frozen; 2-wave triangle tiles + exact merge)
    sq_k<<<BN_ / 4, 256, 0, stream>>>(R0, sqb);
    transpose_nf_k<<<dim3(18, 6, 64), dim3(32, 8), 0, stream>>>(R0, R3);
    knn_sym_k<<<dim3(45, 64), 128, 0, stream>>>(R3, sqb, candV, candI);
    knn_merge_k<<<BN_ / 256, 256, 0, stream>>>(candV, candI, idxb);

    // 3. edge attention — BOTH split-bf16 GEMMs in one dispatch (y 0..5)
    gemm_mfma_split2_k<<<dim3(288, 6), 256, 0, stream>>>(Ahi, Alo,
        waHi, waLo, R1, R2, att_b1);
    edge_att_k<<<E_ / 4, 256, 0, stream>>>(R1, R2, idxb, att_w2, att_b2, att);

    // 4. GNN layer 1 (vectorized msg + bf16 MFMA 256x64)
    msg_bf4_k<float><<<BN_ * 48 / 256, 256, 0, stream>>>(R0, att, idxb, Sb);
    gemm_mfma_k<2><<<dim3(144, 3), 256, 0, stream>>>(Sb, wg1T, Hb,
        BN_, 192, 192, gnn_b1, nullptr, nullptr, nullptr);
    // 5. GNN layer 2
    msg_bf4_k<unsigned short><<<BN_ * 48 / 256, 256, 0, stream>>>(Hb, att, idxb, Sb);
    gemm_mfma_k<2><<<dim3(144, 3), 256, 0, stream>>>(Sb, wg2T, Tb,
        BN_, 192, 192, gnn_b2, nullptr, nullptr, nullptr);

    // 6. FFN full-size (R0/R1 dead -> U overlay)
    gemm_mfma_k<3><<<dim3(144, 12), 256, 0, stream>>>(Tb, wf1T, U,
        BN_, 768, 192, ffn_b1, ffn_g1, ffn_be1, nullptr);
    gemm_mfma_k<4><<<dim3(144, 3), 256, 0, stream>>>(U, wf2T, ToutB,
        BN_, 192, 768, ffn_b2, ffn_g2, ffn_be2, Tb);

    // 7. pool + head (f32, tiny)
    pool_bf16_k<<<64, 192, 0, stream>>>(ToutB, gb);
    gemm_rm_k<3><<<dim3(1, 16), 256, 0, stream>>>(gb, pred_w1, pb,
        64, 1024, 192, pred_b1, pred_g, pred_be, nullptr);
    head2_k<<<64, 256, 0, stream>>>(pb, pred_w2, pred_b2, pred);
}

// Round 13
// 700.849 us; speedup vs baseline: 1.0652x; 1.0652x over previous
//
#include <hip/hip_runtime.h>
#include <hip/hip_bf16.h>
#include <math.h>

// ---------------- problem constants ----------------
constexpr int B_    = 64;
constexpr int C_    = 192;
constexpr int N_    = 576;    // nodes per image (24x24)
constexpr int BN_   = B_ * N_;      // 36864
constexpr int K_    = 5;
constexpr int E_    = BN_ * K_;     // 184320

__device__ __forceinline__ float gelu_exact(float x) {
    return 0.5f * x * (1.0f + erff(x * 0.70710678118654752440f));
}

__device__ __forceinline__ float bf2f(unsigned short v) {
    return __uint_as_float(((unsigned)v) << 16);
}
__device__ __forceinline__ unsigned short f2bf(float x) {
    __hip_bfloat16 h = __float2bfloat16(x);
    return *(unsigned short*)&h;
}

// ---------------- fused weight prep: 6 kernels -> 1 launch ----------------
__global__ __launch_bounds__(256) void prep_all_k(
    const float* __restrict__ stem_w, const float* __restrict__ gnn_w1,
    const float* __restrict__ gnn_w2, const float* __restrict__ ffn_w1,
    const float* __restrict__ ffn_w2, const float* __restrict__ att_w1,
    float* __restrict__ wt, unsigned short* __restrict__ wg1T,
    unsigned short* __restrict__ wg2T, unsigned short* __restrict__ wf1T,
    unsigned short* __restrict__ wf2T, unsigned short* __restrict__ waHi,
    unsigned short* __restrict__ waLo)
{
    int gid = blockIdx.x * 256 + threadIdx.x;        // < 589824
    if (gid < 147456) {                              // transpose_w
        int k = gid / 192, oc = gid % 192;
        wt[gid] = stem_w[oc * 768 + k];
    } else if (gid < 184320) {                       // wg1
        int g = gid - 147456;
        int n = g / 192, k = g % 192;
        wg1T[g] = f2bf(gnn_w1[(size_t)k * 192 + n]);
    } else if (gid < 221184) {                       // wg2
        int g = gid - 184320;
        int n = g / 192, k = g % 192;
        wg2T[g] = f2bf(gnn_w2[(size_t)k * 192 + n]);
    } else if (gid < 368640) {                       // wf1 (K=192,N=768)
        int g = gid - 221184;
        int n = g / 192, k = g % 192;
        wf1T[g] = f2bf(ffn_w1[(size_t)k * 768 + n]);
    } else if (gid < 516096) {                       // wf2 (K=768,N=192)
        int g = gid - 368640;
        int n = g / 768, k = g % 768;
        wf2T[g] = f2bf(ffn_w2[(size_t)k * 192 + n]);
    } else {                                         // wsplit att
        int g = gid - 516096;                        // < 73728
        int half = g / 36864, r = g % 36864;
        int n = r / 192, k = r % 192;
        float v = att_w1[(size_t)(half * 192 + k) * 192 + n];
        unsigned short h = f2bf(v);
        waHi[g] = h;
        waLo[g] = f2bf(v - bf2f(h));
    }
}

// ---------------- stem: 96-row tile GEMM + asplit-only fusion (proven R10) ----------------
__global__ __launch_bounds__(256) void stem_gemm96a_k(
    const float* __restrict__ x, const float* __restrict__ Wt,
    const float* __restrict__ sb, const float* __restrict__ pos,
    float* __restrict__ nf,
    unsigned short* __restrict__ ahi, unsigned short* __restrict__ alo)
{
    __shared__ float As[96][68];
    __shared__ float Ws[64][68];
    const int tid = threadIdx.x;
    const int tr = tid >> 4, tc = tid & 15;
    const int mb = blockIdx.x;          // 0..383 (64 images x 6 tiles of 96)
    const int nb = blockIdx.y;          // 0..2 oc blocks
    const int b  = mb / 6;
    const int n0 = (mb % 6) * 96;       // node offset within image

    float4 acc[6];
    #pragma unroll
    for (int i = 0; i < 6; ++i) acc[i] = float4{0.f, 0.f, 0.f, 0.f};

    for (int kc = 0; kc < 768; kc += 64) {
        #pragma unroll
        for (int i = 0; i < 6; ++i) {
            int q = i * 256 + tid;
            int m = q >> 4, kq = q & 15;       // m < 96
            int k = kc + kq * 4;
            int ci = k >> 8, rem = k & 255, dy = rem >> 4, dx = rem & 15;
            int n = n0 + m, py = n / 24, px = n % 24;
            const float* src = &x[(((size_t)(b * 3 + ci) * 384) + py * 16 + dy) * 384
                                  + px * 16 + dx];
            *(float4*)&As[m][kq * 4] = *(const float4*)src;
        }
        #pragma unroll
        for (int i = 0; i < 4; ++i) {
            int q = i * 256 + tid;
            int m = q >> 4, kq = q & 15;       // m < 64
            *(float4*)&Ws[m][kq * 4] =
                *(const float4*)&Wt[(size_t)(kc + m) * 192 + nb * 64 + kq * 4];
        }
        __syncthreads();
        #pragma unroll
        for (int k4 = 0; k4 < 64; k4 += 4) {
            float4 a4[6], b4[4];
            #pragma unroll
            for (int i = 0; i < 6; ++i) a4[i] = *(const float4*)&As[tr * 6 + i][k4];
            #pragma unroll
            for (int kk = 0; kk < 4; ++kk) b4[kk] = *(const float4*)&Ws[k4 + kk][tc * 4];
            #pragma unroll
            for (int i = 0; i < 6; ++i) {
                const float av[4] = {a4[i].x, a4[i].y, a4[i].z, a4[i].w};
                #pragma unroll
                for (int kk = 0; kk < 4; ++kk) {
                    acc[i].x += av[kk] * b4[kk].x;
                    acc[i].y += av[kk] * b4[kk].y;
                    acc[i].z += av[kk] * b4[kk].z;
                    acc[i].w += av[kk] * b4[kk].w;
                }
            }
        }
        __syncthreads();
    }

    #pragma unroll
    for (int i = 0; i < 6; ++i) {
        int n = n0 + tr * 6 + i;
        int row = b * 576 + n;
        int oc0 = nb * 64 + tc * 4;
        float v[4] = {acc[i].x, acc[i].y, acc[i].z, acc[i].w};
        unsigned short hv[4], lv[4];
        #pragma unroll
        for (int j = 0; j < 4; ++j) {
            int oc = oc0 + j;
            v[j] = v[j] + sb[oc] + pos[oc * 576 + n];
            hv[j] = f2bf(v[j]);
            lv[j] = f2bf(v[j] - bf2f(hv[j]));
        }
        *(float4*)&nf[(size_t)row * 192 + oc0] = float4{v[0], v[1], v[2], v[3]};
        *(ushort4*)&ahi[(size_t)row * 192 + oc0] = ushort4{hv[0], hv[1], hv[2], hv[3]};
        *(ushort4*)&alo[(size_t)row * 192 + oc0] = ushort4{lv[0], lv[1], lv[2], lv[3]};
    }
}

// ---------------- transpose nf per image (proven) ----------------
__global__ void transpose_nf_k(const float* __restrict__ nf, float* __restrict__ nfT) {
    __shared__ float tile[32][33];
    int b = blockIdx.z;
    int n0 = blockIdx.x * 32, c0 = blockIdx.y * 32;
    int tx = threadIdx.x, ty = threadIdx.y;   // 32 x 8
    #pragma unroll
    for (int r = 0; r < 4; ++r) {
        int i = ty * 4 + r;
        tile[i][tx] = nf[((size_t)b * 576 + n0 + i) * 192 + c0 + tx];
    }
    __syncthreads();
    #pragma unroll
    for (int r = 0; r < 4; ++r) {
        int i = ty * 4 + r;
        nfT[((size_t)b * 192 + c0 + i) * 576 + n0 + tx] = tile[tx][i];
    }
}

// ---------------- sq norms per node (UNCHANGED) ----------------
__global__ __launch_bounds__(256) void sq_k(const float* __restrict__ nf,
                                            float* __restrict__ sq) {
    int wid = threadIdx.x >> 6, lane = threadIdx.x & 63;
    int n = blockIdx.x * 4 + wid;
    const float* row = nf + (size_t)n * 192;
    float s = 0.f;
    #pragma unroll
    for (int c = 0; c < 3; ++c) { float v = row[lane + c * 64]; s += v * v; }
    #pragma unroll
    for (int off = 32; off; off >>= 1) s += __shfl_down(s, off);
    if (lane == 0) sq[n] = s;
}

// ---------------- kNN symmetric-triangle tile kernel (PROVEN R1 64-thread, ~168us) ----------------
// Restructure scoreboard (all bit-exact, all slower): 256thr/4x4=187,
// 64thr/9.2KB=198, 128thr/2wave=199.  64thr/8x8 maximizes FMA:DS ratio
// (16) AND per-thread ILP; closed at ~168us.
__global__ __launch_bounds__(64) void knn_sym_k(
    const float* __restrict__ nfT, const float* __restrict__ sqn,
    float* __restrict__ candV, int* __restrict__ candI)
{
    __shared__ float smem[64 * 69];          // 17664 B
    float* As  = smem;                       // [32][64] k-major (GEMM phase)
    float* Bs  = smem + 2048;                // [32][64]
    float* d2s = smem;                       // [64][69] (selection phase)

    const int tid = threadIdx.x;             // 0..63
    const int tr = tid >> 3, tc = tid & 7;   // 8x8 thread grid
    const int b = blockIdx.y;
    int t = blockIdx.x;                      // 0..44 upper-triangle tile id
    int bi = 0;
    while (t >= 9 - bi) { t -= 9 - bi; ++bi; }
    const int bj = bi + t;
    const int r0 = bi * 64, c0 = bj * 64;

    float acc[8][8];
    #pragma unroll
    for (int i = 0; i < 8; ++i)
        #pragma unroll
        for (int j = 0; j < 8; ++j) acc[i][j] = 0.f;

    for (int kc = 0; kc < 192; kc += 32) {
        // stage 32 k-rows x 64 nodes for each operand, both from nfT (coalesced)
        #pragma unroll
        for (int i = 0; i < 8; ++i) {
            int q = i * 64 + tid;            // 0..511
            int k = q >> 4, c4 = (q & 15) * 4;
            const float* srow = &nfT[((size_t)(b * 192 + kc + k)) * 576];
            *(float4*)&As[k * 64 + c4] = *(const float4*)&srow[r0 + c4];
            *(float4*)&Bs[k * 64 + c4] = *(const float4*)&srow[c0 + c4];
        }
        __syncthreads();
        #pragma unroll 8
        for (int kk = 0; kk < 32; ++kk) {
            float4 a0 = *(const float4*)&As[kk * 64 + tr * 8];
            float4 a1 = *(const float4*)&As[kk * 64 + tr * 8 + 4];
            float4 b0 = *(const float4*)&Bs[kk * 64 + tc * 8];
            float4 b1 = *(const float4*)&Bs[kk * 64 + tc * 8 + 4];
            const float av[8] = {a0.x, a0.y, a0.z, a0.w, a1.x, a1.y, a1.z, a1.w};
            const float bv[8] = {b0.x, b0.y, b0.z, b0.w, b1.x, b1.y, b1.z, b1.w};
            #pragma unroll
            for (int i = 0; i < 8; ++i)
                #pragma unroll
                for (int j = 0; j < 8; ++j)
                    acc[i][j] += av[i] * bv[j];
        }
        __syncthreads();
    }

    // epilogue into LDS (overlays As/Bs — synced above)
    #pragma unroll
    for (int i = 0; i < 8; ++i) {
        int rl = tr * 8 + i, rg = r0 + rl;
        float sr = sqn[b * 576 + rg];
        #pragma unroll
        for (int j = 0; j < 8; ++j) {
            int cl = tc * 8 + j, cg = c0 + cl;
            float d = sr + sqn[b * 576 + cg] - 2.f * acc[i][j];
            if (cg == rg) d += 1e9f;
            d2s[rl * 69 + cl] = d;
        }
    }
    __syncthreads();

    // pass A: rows of group bi, candidate columns = group bj (ascending scan)
    {
        const int r = tid;
        float tv[5]; int ti[5];
        #pragma unroll
        for (int p = 0; p < 5; ++p) { tv[p] = 3.4e38f; ti[p] = 0; }
        for (int c = 0; c < 64; ++c) {
            float cv = d2s[r * 69 + c];
            if (cv < tv[4]) {
                int ci = c0 + c;
                #pragma unroll
                for (int q = 0; q < 5; ++q) {       // stable sorted insert (strict <)
                    bool less = cv < tv[q];
                    float nv = less ? tv[q] : cv;
                    int ni   = less ? ti[q] : ci;
                    tv[q] = less ? cv : tv[q];
                    ti[q] = less ? ci : ti[q];
                    cv = nv; ci = ni;
                }
            }
        }
        int gr = b * 576 + r0 + r;
        #pragma unroll
        for (int p = 0; p < 5; ++p) {
            candV[(size_t)gr * 45 + bj * 5 + p] = tv[p];
            candI[(size_t)gr * 45 + bj * 5 + p] = ti[p];
        }
    }

    // pass B (off-diagonal only): rows of group bj, candidate cols = group bi
    if (bi != bj) {
        const int c = tid;
        float tv[5]; int ti[5];
        #pragma unroll
        for (int p = 0; p < 5; ++p) { tv[p] = 3.4e38f; ti[p] = 0; }
        for (int r = 0; r < 64; ++r) {
            float cv = d2s[r * 69 + c];          // transposed read, stride-69 rows
            if (cv < tv[4]) {
                int ci = r0 + r;
                #pragma unroll
                for (int q = 0; q < 5; ++q) {
                    bool less = cv < tv[q];
                    float nv = less ? tv[q] : cv;
                    int ni   = less ? ti[q] : ci;
                    tv[q] = less ? cv : tv[q];
                    ti[q] = less ? ci : ti[q];
                    cv = nv; ci = ni;
                }
            }
        }
        int gr = b * 576 + c0 + c;
        #pragma unroll
        for (int p = 0; p < 5; ++p) {
            candV[(size_t)gr * 45 + bi * 5 + p] = tv[p];
            candI[(size_t)gr * 45 + bi * 5 + p] = ti[p];
        }
    }
}

// ---------------- kNN merge: 9 groups x 5 sorted candidates -> final top-5 ----------------
__global__ __launch_bounds__(256) void knn_merge_k(
    const float* __restrict__ candV, const int* __restrict__ candI,
    int* __restrict__ idxOut)
{
    int r = blockIdx.x * 256 + threadIdx.x;    // < BN_
    float tv[5]; int ti[5];
    #pragma unroll
    for (int p = 0; p < 5; ++p) { tv[p] = 3.4e38f; ti[p] = 0; }
    #pragma unroll 5
    for (int s = 0; s < 45; ++s) {
        float cv = candV[(size_t)r * 45 + s];
        if (cv < tv[4]) {
            int cidx = candI[(size_t)r * 45 + s];
            #pragma unroll
            for (int q = 0; q < 5; ++q) {
                bool less = cv < tv[q];
                float nv = less ? tv[q] : cv;
                int ni   = less ? ti[q] : cidx;
                tv[q] = less ? cv : tv[q];
                ti[q] = less ? cidx : ti[q];
                cv = nv; cidx = ni;
            }
        }
    }
    int base = (r / 576) * 576;
    #pragma unroll
    for (int p = 0; p < 5; ++p) idxOut[r * 5 + p] = base + ti[p];
}

// ---------------- generic 64x64-tile f32 GEMM (head) ----------------
template <int EPI>
__global__ __launch_bounds__(256) void gemm_rm_k(
    const float* __restrict__ A, const float* __restrict__ W, float* __restrict__ out,
    int M, int N, int K,
    const float* __restrict__ bias, const float* __restrict__ gsc,
    const float* __restrict__ gsh, const float* __restrict__ res)
{
    __shared__ float As[64][68];
    __shared__ float Ws[64][68];
    const int tid = threadIdx.x;
    const int tr = tid >> 4, tc = tid & 15;
    const int mBase = blockIdx.x * 64, nBase = blockIdx.y * 64;

    float4 acc[4];
    acc[0] = acc[1] = acc[2] = acc[3] = float4{0.f, 0.f, 0.f, 0.f};

    for (int kc = 0; kc < K; kc += 64) {
        #pragma unroll
        for (int i = 0; i < 4; ++i) {
            int q = i * 256 + tid;
            int m = q >> 4, kq = q & 15;
            *(float4*)&As[m][kq * 4] =
                *(const float4*)&A[(size_t)(mBase + m) * K + kc + kq * 4];
            *(float4*)&Ws[m][kq * 4] =
                *(const float4*)&W[(size_t)(kc + m) * N + nBase + kq * 4];
        }
        __syncthreads();
        #pragma unroll
        for (int k4 = 0; k4 < 64; k4 += 4) {
            float4 a4[4], b4[4];
            #pragma unroll
            for (int i = 0; i < 4; ++i) a4[i] = *(const float4*)&As[tr * 4 + i][k4];
            #pragma unroll
            for (int kk = 0; kk < 4; ++kk) b4[kk] = *(const float4*)&Ws[k4 + kk][tc * 4];
            #pragma unroll
            for (int i = 0; i < 4; ++i) {
                const float av[4] = {a4[i].x, a4[i].y, a4[i].z, a4[i].w};
                #pragma unroll
                for (int kk = 0; kk < 4; ++kk) {
                    acc[i].x += av[kk] * b4[kk].x;
                    acc[i].y += av[kk] * b4[kk].y;
                    acc[i].z += av[kk] * b4[kk].z;
                    acc[i].w += av[kk] * b4[kk].w;
                }
            }
        }
        __syncthreads();
    }

    #pragma unroll
    for (int i = 0; i < 4; ++i) {
        int row = mBase + tr * 4 + i;
        int n0 = nBase + tc * 4;
        float v[4] = {acc[i].x, acc[i].y, acc[i].z, acc[i].w};
        #pragma unroll
        for (int j = 0; j < 4; ++j) {
            int n = n0 + j;
            float xv = v[j];
            if (EPI == 1) xv += bias[n];
            if (EPI == 2) { xv += bias[n]; xv = fmaxf(xv, 0.f); }
            if (EPI == 3) { xv = (xv + bias[n]) * gsc[n] + gsh[n]; xv = gelu_exact(xv); }
            if (EPI == 4) {
                xv = res[(size_t)row * N + n] + (xv + bias[n]) * gsc[n] + gsh[n];
            }
            v[j] = xv;
        }
        *(float4*)&out[(size_t)row * N + n0] = float4{v[0], v[1], v[2], v[3]};
    }
}

// ---------------- bf16 MFMA GEMM, 256x64 tile (proven R4) ----------------
template <int EPI>
__global__ __launch_bounds__(256) void gemm_mfma_k(
    const unsigned short* __restrict__ A, const unsigned short* __restrict__ Bt,
    unsigned short* __restrict__ out, int M, int N, int K,
    const float* __restrict__ bias, const float* __restrict__ gsc,
    const float* __restrict__ gsh, const unsigned short* __restrict__ res)
{
    using frag = __attribute__((ext_vector_type(8))) short;
    using facc = __attribute__((ext_vector_type(4))) float;
    __shared__ unsigned short As[256][72];  // [m][k]  36.9KB
    __shared__ unsigned short Bs[64][72];   // [n][k]   9.2KB
    const int tid = threadIdx.x;
    const int wave = tid >> 6, lane = tid & 63;
    const int m16 = lane & 15, quad = lane >> 4;
    const int mBase = blockIdx.x * 256, nBase = blockIdx.y * 64;

    facc zero = {0.f, 0.f, 0.f, 0.f};
    facc acc[4][4];                         // [m-slice][n-tile]
    #pragma unroll
    for (int ms = 0; ms < 4; ++ms)
        #pragma unroll
        for (int t = 0; t < 4; ++t) acc[ms][t] = zero;

    for (int kc = 0; kc < K; kc += 64) {
        #pragma unroll
        for (int r = 0; r < 8; ++r) {       // A: 256 rows x 64 k
            int q = r * 256 + tid;          // 0..2047
            int row = q >> 3, c8 = (q & 7) * 8;
            *(int4*)&As[row][c8] =
                *(const int4*)&A[(size_t)(mBase + row) * K + kc + c8];
        }
        #pragma unroll
        for (int r = 0; r < 2; ++r) {       // B: 64 rows x 64 k
            int q = r * 256 + tid;          // 0..511
            int row = q >> 3, c8 = (q & 7) * 8;
            *(int4*)&Bs[row][c8] =
                *(const int4*)&Bt[(size_t)(nBase + row) * K + kc + c8];
        }
        __syncthreads();
        #pragma unroll
        for (int kk = 0; kk < 64; kk += 32) {
            frag bfr[4];
            #pragma unroll
            for (int t = 0; t < 4; ++t)
                bfr[t] = *(const frag*)&Bs[t * 16 + m16][kk + quad * 8];
            #pragma unroll
            for (int ms = 0; ms < 4; ++ms) {
                frag a = *(const frag*)&As[64 * wave + ms * 16 + m16][kk + quad * 8];
                #pragma unroll
                for (int t = 0; t < 4; ++t)
                    acc[ms][t] = __builtin_amdgcn_mfma_f32_16x16x32_bf16(a, bfr[t], acc[ms][t], 0, 0, 0);
            }
        }
        __syncthreads();
    }

    #pragma unroll
    for (int ms = 0; ms < 4; ++ms) {
        #pragma unroll
        for (int t = 0; t < 4; ++t) {
            #pragma unroll
            for (int r = 0; r < 4; ++r) {
                int row = mBase + 64 * wave + ms * 16 + quad * 4 + r;
                int col = nBase + t * 16 + m16;
                float xv = acc[ms][t][r];
                if (EPI == 2) { xv += bias[col]; xv = fmaxf(xv, 0.f); }
                if (EPI == 3) { xv = (xv + bias[col]) * gsc[col] + gsh[col]; xv = gelu_exact(xv); }
                if (EPI == 4) {
                    xv = bf2f(res[(size_t)row * N + col]) + (xv + bias[col]) * gsc[col] + gsh[col];
                }
                out[(size_t)row * N + col] = f2bf(xv);
            }
        }
    }
}

// ---------------- merged split-bf16 MFMA GEMM: both att halves in ONE launch ----------------
__global__ __launch_bounds__(256) void gemm_mfma_split2_k(
    const unsigned short* __restrict__ Ah, const unsigned short* __restrict__ Al,
    const unsigned short* __restrict__ waHi, const unsigned short* __restrict__ waLo,
    float* __restrict__ outA, float* __restrict__ outB,
    const float* __restrict__ bias)
{
    using frag = __attribute__((ext_vector_type(8))) short;
    using facc = __attribute__((ext_vector_type(4))) float;
    __shared__ unsigned short AsH[128][72], AsL[128][72];   // 2x18.4KB
    __shared__ unsigned short BsH[64][72],  BsL[64][72];    // 2x9.2KB
    const int tid = threadIdx.x;
    const int wave = tid >> 6, lane = tid & 63;
    const int m16 = lane & 15, quad = lane >> 4;
    const int half = blockIdx.y / 3;
    const int mBase = blockIdx.x * 128, nBase = (blockIdx.y % 3) * 64;
    const unsigned short* Bh = waHi + half * 36864;
    const unsigned short* Bl = waLo + half * 36864;
    float* out = half ? outB : outA;
    constexpr int K = 192;

    facc zero = {0.f, 0.f, 0.f, 0.f};
    facc acc[2][4];                         // [m-slice][n-tile]
    #pragma unroll
    for (int ms = 0; ms < 2; ++ms)
        #pragma unroll
        for (int t = 0; t < 4; ++t) acc[ms][t] = zero;

    for (int kc = 0; kc < K; kc += 64) {
        #pragma unroll
        for (int r = 0; r < 4; ++r) {       // A: 128 rows x 64 k per buffer
            int q = r * 256 + tid;          // 0..1023
            int row = q >> 3, c8 = (q & 7) * 8;
            *(int4*)&AsH[row][c8] = *(const int4*)&Ah[(size_t)(mBase + row) * K + kc + c8];
            *(int4*)&AsL[row][c8] = *(const int4*)&Al[(size_t)(mBase + row) * K + kc + c8];
        }
        #pragma unroll
        for (int r = 0; r < 2; ++r) {       // B: 64 rows x 64 k per buffer
            int q = r * 256 + tid;          // 0..511
            int row = q >> 3, c8 = (q & 7) * 8;
            *(int4*)&BsH[row][c8] = *(const int4*)&Bh[(size_t)(nBase + row) * K + kc + c8];
            *(int4*)&BsL[row][c8] = *(const int4*)&Bl[(size_t)(nBase + row) * K + kc + c8];
        }
        __syncthreads();
        #pragma unroll
        for (int kk = 0; kk < 64; kk += 32) {
            frag bh[4], bl[4];
            #pragma unroll
            for (int t = 0; t < 4; ++t) {
                bh[t] = *(const frag*)&BsH[t * 16 + m16][kk + quad * 8];
                bl[t] = *(const frag*)&BsL[t * 16 + m16][kk + quad * 8];
            }
            #pragma unroll
            for (int ms = 0; ms < 2; ++ms) {
                frag ah = *(const frag*)&AsH[32 * wave + ms * 16 + m16][kk + quad * 8];
                frag al = *(const frag*)&AsL[32 * wave + ms * 16 + m16][kk + quad * 8];
                #pragma unroll
                for (int t = 0; t < 4; ++t) {
                    acc[ms][t] = __builtin_amdgcn_mfma_f32_16x16x32_bf16(ah, bh[t], acc[ms][t], 0, 0, 0);
                    acc[ms][t] = __builtin_amdgcn_mfma_f32_16x16x32_bf16(ah, bl[t], acc[ms][t], 0, 0, 0);
                    acc[ms][t] = __builtin_amdgcn_mfma_f32_16x16x32_bf16(al, bh[t], acc[ms][t], 0, 0, 0);
                }
            }
        }
        __syncthreads();
    }

    #pragma unroll
    for (int ms = 0; ms < 2; ++ms) {
        #pragma unroll
        for (int t = 0; t < 4; ++t) {
            #pragma unroll
            for (int r = 0; r < 4; ++r) {
                int row = mBase + 32 * wave + ms * 16 + quad * 4 + r;
                int col = nBase + t * 16 + m16;
                float xv = acc[ms][t][r];
                if (half) xv += bias[col];
                out[(size_t)row * 192 + col] = xv;
            }
        }
    }
}

// ---------------- edge attention v2: one wave per dst node (5 edges) ----------------
// Per-edge math identical to edge_att_k: lane c computes v = hA[src]+hB[dst],
// relu, s += v*w2[c] over c0 ascending; same shfl_down reduce; same sigmoid.
// hB row loaded ONCE per dst (was 5x) -> global traffic 283MB -> ~170MB,
// blocks 46080 -> 9216.
__global__ __launch_bounds__(256) void edge_att5_k(
    const float* __restrict__ hA, const float* __restrict__ hB,
    const int* __restrict__ idx, const float* __restrict__ w2,
    const float* __restrict__ b2, float* __restrict__ att)
{
    int wid = threadIdx.x >> 6, lane = threadIdx.x & 63;
    int dst = blockIdx.x * 4 + wid;          // < BN_
    float hb[3], w[3];
    #pragma unroll
    for (int c0 = 0; c0 < 3; ++c0) {
        hb[c0] = hB[(size_t)dst * 192 + lane + c0 * 64];
        w[c0]  = w2[lane + c0 * 64];
    }
    float s[K_];
    #pragma unroll
    for (int p = 0; p < K_; ++p) {
        int src = idx[dst * K_ + p];
        float sp = 0.f;
        #pragma unroll
        for (int c0 = 0; c0 < 3; ++c0) {
            float v = hA[(size_t)src * 192 + lane + c0 * 64] + hb[c0];
            v = fmaxf(v, 0.f);
            sp += v * w[c0];
        }
        s[p] = sp;
    }
    #pragma unroll
    for (int p = 0; p < K_; ++p) {
        float sp = s[p];
        #pragma unroll
        for (int off = 32; off; off >>= 1) sp += __shfl_down(sp, off);
        if (lane == 0) att[dst * K_ + p] = 1.f / (1.f + expf(-(sp + b2[0])));
    }
}

// ---------------- message passing v2: 4 channels/thread, vectorized ----------------
__device__ __forceinline__ void ldv4(const float* p, size_t i, float* o) {
    float4 v = *(const float4*)&p[i];
    o[0] = v.x; o[1] = v.y; o[2] = v.z; o[3] = v.w;
}
__device__ __forceinline__ void ldv4(const unsigned short* p, size_t i, float* o) {
    ushort4 v = *(const ushort4*)&p[i];
    o[0] = bf2f(v.x); o[1] = bf2f(v.y); o[2] = bf2f(v.z); o[3] = bf2f(v.w);
}

template <typename TI>
__global__ __launch_bounds__(256) void msg_bf4_k(
    const TI* __restrict__ h, const float* __restrict__ att,
    const int* __restrict__ idx, unsigned short* __restrict__ s)
{
    int g4 = blockIdx.x * 256 + threadIdx.x;   // < BN*48
    int n = g4 / 48, c4 = (g4 % 48) * 4;
    int sp[K_]; float aw[K_];
    #pragma unroll
    for (int p = 0; p < K_; ++p) {
        sp[p] = idx[n * K_ + p];
        aw[p] = att[n * K_ + p];
    }
    float acc[4];
    ldv4(h, (size_t)n * 192 + c4, acc);
    #pragma unroll
    for (int p = 0; p < K_; ++p) {
        float v[4];
        ldv4(h, (size_t)sp[p] * 192 + c4, v);
        #pragma unroll
        for (int j = 0; j < 4; ++j) acc[j] += aw[p] * v[j];
    }
    ushort4 o;
    o.x = f2bf(acc[0]); o.y = f2bf(acc[1]); o.z = f2bf(acc[2]); o.w = f2bf(acc[3]);
    *(ushort4*)&s[(size_t)n * 192 + c4] = o;
}

// ---------------- global average pool over nodes (bf16 in) ----------------
__global__ void pool_bf16_k(const unsigned short* __restrict__ t, float* __restrict__ g) {
    int b = blockIdx.x, c = threadIdx.x;   // 192 threads
    float s = 0.f;
    for (int n = 0; n < 576; ++n) s += bf2f(t[((size_t)b * 576 + n) * 192 + c]);
    g[b * 192 + c] = s * (1.f / 576.f);
}

// ---------------- head reduce (UNCHANGED) ----------------
__global__ __launch_bounds__(256) void head2_k(
    const float* __restrict__ p, const float* __restrict__ w2,
    const float* __restrict__ b2, float* __restrict__ out)
{
    int b = blockIdx.x;
    float s = 0.f;
    for (int j = threadIdx.x; j < 1024; j += 256) s += p[(size_t)b * 1024 + j] * w2[j];
    #pragma unroll
    for (int off = 32; off; off >>= 1) s += __shfl_down(s, off);
    __shared__ float ls[4];
    int wid = threadIdx.x >> 6, lane = threadIdx.x & 63;
    if (lane == 0) ls[wid] = s;
    __syncthreads();
    if (threadIdx.x == 0) out[b] = ls[0] + ls[1] + ls[2] + ls[3] + b2[0];
}

// ---------------- launch ----------------
extern "C" void kernel_launch(void* const* d_in, const int* in_sizes, int n_in,
                              void* d_out, int out_size, void* d_ws, size_t ws_size,
                              hipStream_t stream) {
    const float* x        = (const float*)d_in[0];
    const float* stem_w   = (const float*)d_in[1];
    const float* stem_b   = (const float*)d_in[2];
    const float* pos      = (const float*)d_in[3];
    const float* att_w1   = (const float*)d_in[4];
    const float* att_b1   = (const float*)d_in[5];
    const float* att_w2   = (const float*)d_in[6];
    const float* att_b2   = (const float*)d_in[7];
    const float* gnn_w1   = (const float*)d_in[8];
    const float* gnn_b1   = (const float*)d_in[9];
    const float* gnn_w2   = (const float*)d_in[10];
    const float* gnn_b2   = (const float*)d_in[11];
    const float* ffn_w1   = (const float*)d_in[12];
    const float* ffn_b1   = (const float*)d_in[13];
    const float* ffn_g1   = (const float*)d_in[14];
    const float* ffn_be1  = (const float*)d_in[15];
    const float* ffn_w2   = (const float*)d_in[16];
    const float* ffn_b2   = (const float*)d_in[17];
    const float* ffn_g2   = (const float*)d_in[18];
    const float* ffn_be2  = (const float*)d_in[19];
    const float* pred_w1  = (const float*)d_in[20];
    const float* pred_b1  = (const float*)d_in[21];
    const float* pred_g   = (const float*)d_in[22];
    const float* pred_be  = (const float*)d_in[23];
    const float* pred_w2  = (const float*)d_in[24];
    const float* pred_b2  = (const float*)d_in[25];

    float* ws = (float*)d_ws;
    const size_t RSZ = (size_t)BN_ * C_;          // 7,077,888 floats
    float* R0 = ws;               // nf (f32) — dead after msg layer 1 -> U (FFN)
    float* R1 = R0 + RSZ;         // cand -> hA -> [Sb | Hb] -> U (FFN, with R0)
    float* R2 = R1 + RSZ;         // hB (f32) -> [Tb | ToutB] bf16
    float* R3 = R2 + RSZ;         // nfT
    float* sqb = R3 + RSZ;        // BN
    int*   idxb = (int*)(sqb + BN_);              // E ints
    float* gb = (float*)(idxb + E_);              // 64*192
    float* pb = gb + 64 * C_;                     // 64*1024
    unsigned short* wg1T = (unsigned short*)(pb + 64 * 1024);  // [192][192]
    unsigned short* wg2T = wg1T + 192 * 192;
    unsigned short* wf1T = wg2T + 192 * 192;      // [768][192]
    unsigned short* wf2T = wf1T + 768 * 192;      // [192][768]
    unsigned short* waHi = wf2T + 192 * 768;      // [2][192][192]
    unsigned short* waLo = waHi + 2 * 192 * 192;
    float* Wt = (float*)(waLo + 2 * 192 * 192);   // stem Wt [768][192] (dedicated)
    unsigned short* Ahi = (unsigned short*)(Wt + 768 * 192);   // BN x 192 bf16 hi
    unsigned short* Alo = Ahi + RSZ;                            // BN x 192 bf16 lo

    // kNN candidate buffers live in R1 (dead before R1's next use in step 3)
    float* candV = R1;                                   // BN x 45
    int*   candI = (int*)(R1 + (size_t)BN_ * 45);        // BN x 45

    unsigned short* Sb    = (unsigned short*)R1;             // BN x 192 bf16
    unsigned short* Hb    = (unsigned short*)(R1 + RSZ / 2);
    unsigned short* Tb    = (unsigned short*)R2;
    unsigned short* ToutB = (unsigned short*)(R2 + RSZ / 2);
    // full-size FFN intermediate: BN x 768 bf16 = 56.6MB = R0+R1 exactly
    unsigned short* U     = (unsigned short*)R0;

    float* att  = (float*)d_out;                  // E
    float* pred = att + E_;                       // 64

    // 0. all weight prep in ONE launch
    prep_all_k<<<2304, 256, 0, stream>>>(stem_w, gnn_w1, gnn_w2, ffn_w1,
        ffn_w2, att_w1, Wt, wg1T, wg2T, wf1T, wf2T, waHi, waLo);

    // 1. stem (proven 96-row tile, bit-frozen FMA chain) + asplit-only fusion
    stem_gemm96a_k<<<dim3(384, 3), 256, 0, stream>>>(x, Wt, stem_b, pos,
        R0, Ahi, Alo);

    // 2. kNN graph (d2 math frozen; proven 64-thread triangle tiles)
    sq_k<<<BN_ / 4, 256, 0, stream>>>(R0, sqb);
    transpose_nf_k<<<dim3(18, 6, 64), dim3(32, 8), 0, stream>>>(R0, R3);
    knn_sym_k<<<dim3(45, 64), 64, 0, stream>>>(R3, sqb, candV, candI);
    knn_merge_k<<<BN_ / 256, 256, 0, stream>>>(candV, candI, idxb);

    // 3. edge attention — BOTH split-bf16 GEMMs in one dispatch (y 0..5)
    gemm_mfma_split2_k<<<dim3(288, 6), 256, 0, stream>>>(Ahi, Alo,
        waHi, waLo, R1, R2, att_b1);
    edge_att5_k<<<BN_ / 4, 256, 0, stream>>>(R1, R2, idxb, att_w2, att_b2, att);

    // 4. GNN layer 1 (vectorized msg + bf16 MFMA 256x64)
    msg_bf4_k<float><<<BN_ * 48 / 256, 256, 0, stream>>>(R0, att, idxb, Sb);
    gemm_mfma_k<2><<<dim3(144, 3), 256, 0, stream>>>(Sb, wg1T, Hb,
        BN_, 192, 192, gnn_b1, nullptr, nullptr, nullptr);
    // 5. GNN layer 2
    msg_bf4_k<unsigned short><<<BN_ * 48 / 256, 256, 0, stream>>>(Hb, att, idxb, Sb);
    gemm_mfma_k<2><<<dim3(144, 3), 256, 0, stream>>>(Sb, wg2T, Tb,
        BN_, 192, 192, gnn_b2, nullptr, nullptr, nullptr);

    // 6. FFN full-size (R0/R1 dead -> U overlay)
    gemm_mfma_k<3><<<dim3(144, 12), 256, 0, stream>>>(Tb, wf1T, U,
        BN_, 768, 192, ffn_b1, ffn_g1, ffn_be1, nullptr);
    gemm_mfma_k<4><<<dim3(144, 3), 256, 0, stream>>>(U, wf2T, ToutB,
        BN_, 192, 768, ffn_b2, ffn_g2, ffn_be2, Tb);

    // 7. pool + head (f32, tiny)
    pool_bf16_k<<<64, 192, 0, stream>>>(ToutB, gb);
    gemm_rm_k<3><<<dim3(1, 16), 256, 0, stream>>>(gb, pred_w1, pb,
        64, 1024, 192, pred_b1, pred_g, pred_be, nullptr);
    head2_k<<<64, 256, 0, stream>>>(pb, pred_w2, pred_b2, pred);
}